// Round 10
// baseline (259.512 us; speedup 1.0000x reference)
//
#include <hip/hip_runtime.h>
#include <stdint.h>

typedef __bf16 bf16;
typedef float   f32x4   __attribute__((ext_vector_type(4)));
typedef float   float4v __attribute__((ext_vector_type(4)));
typedef bf16    bf16x8  __attribute__((ext_vector_type(8)));
typedef bf16    bf16x4  __attribute__((ext_vector_type(4)));
typedef __fp16  half2   __attribute__((ext_vector_type(2)));   // matches builtin 'h'
typedef __fp16  half4   __attribute__((ext_vector_type(4)));

#define B_ 4
#define S_ 2048
#define D_ 1024
#define H_ 16
#define E_ 64
#define M_ 8192   // B_*S_
// Q prescale: 1/sqrt(E) * log2(e)  -> scores come out in log2 domain
#define QSCALE 0.18033688f

// NOTE (session journal): inline `s_waitcnt` asm (R2/R3) and
// prefetch-after-barrier staging (R5/R6) each killed the MI355X container
// twice. Stage -> __syncthreads -> compute (R1/R4/R7/R8) is proven. Do not
// reintroduce either construct.
// R8: attn was DS-issue-bound (~36 b128-equiv per t-iter ~= measured 60us).
// R9: compile error only — cvt_pkrtz/mfma-f16 builtins use __fp16 vectors,
// not _Float16. R10 = R9 logic with __fp16 typedefs.

// async global->LDS, 16B per lane. LDS dest must be wave-uniform base + lane*16.
__device__ __forceinline__ void async_ld16(const void* g, void* l) {
  __builtin_amdgcn_global_load_lds(
      (const __attribute__((address_space(1))) void*)g,
      (__attribute__((address_space(3))) void*)l, 16, 0, 0);
}

// ---------------- pack kernels ----------------

__global__ __launch_bounds__(256) void pack_x(const float* __restrict__ x,
                                              bf16* __restrict__ xb, int n4) {
  int i = blockIdx.x * 256 + threadIdx.x;
  if (i < n4) {
    float4v v = ((const float4v*)x)[i];
    bf16x4 o = { (bf16)v.x, (bf16)v.y, (bf16)v.z, (bf16)v.w };
    ((bf16x4*)xb)[i] = o;
  }
}

// Wq/Wk/Wv [H][D][E] -> Bt[n][d], n = qkv*1024 + h*64 + e   (K-major transpose)
__global__ __launch_bounds__(256) void pack_wqkv(const float* __restrict__ Wq,
                                                 const float* __restrict__ Wk,
                                                 const float* __restrict__ Wv,
                                                 bf16* __restrict__ Bt) {
  __shared__ float t[64][65];
  const int mat = blockIdx.x;          // 0..47 : qkv*16 + h
  const int qkv = mat >> 4, h = mat & 15;
  const float* W = (qkv == 0) ? Wq : ((qkv == 1) ? Wk : Wv);
  const float* src = W + h * (D_ * E_);         // [d][e]
  const int d0 = blockIdx.y * 64;
  const int tr = threadIdx.x >> 2;              // 0..63
  const int tc = (threadIdx.x & 3) * 16;        // 0,16,32,48
  for (int i = 0; i < 16; ++i) t[tr][tc + i] = src[(d0 + tr) * E_ + tc + i];
  __syncthreads();
  const int n = qkv * 1024 + h * 64 + tr;       // output row (e dim)
  bf16* dst = Bt + n * D_ + d0 + tc;
  for (int i = 0; i < 16; ++i) dst[i] = (bf16)t[tc + i][tr];
}

// Wo [K=1024][N=1024] -> Wot[n][k]
__global__ __launch_bounds__(256) void pack_wo(const float* __restrict__ Wo,
                                               bf16* __restrict__ Wot) {
  __shared__ float t[64][65];
  const int k0 = blockIdx.x * 64, n0 = blockIdx.y * 64;
  const int tr = threadIdx.x >> 2;
  const int tc = (threadIdx.x & 3) * 16;
  for (int i = 0; i < 16; ++i) t[tr][tc + i] = Wo[(k0 + tr) * D_ + n0 + tc + i];
  __syncthreads();
  bf16* dst = Wot + (n0 + tr) * D_ + k0 + tc;
  for (int i = 0; i < 16; ++i) dst[i] = (bf16)t[tc + i][tr];
}

// ---------------- 128x128 MFMA GEMM (m97 structure, XOR-swizzled LDS) ----------

template <int EPI>
__global__ __launch_bounds__(256, 2) void gemm128(
    const bf16* __restrict__ A, const bf16* __restrict__ Bt, int K,
    bf16* __restrict__ qo, bf16* __restrict__ ko, bf16* __restrict__ vt,
    const float* __restrict__ xres, float* __restrict__ outp) {
  __shared__ bf16 As[128 * 64];
  __shared__ bf16 Bs[128 * 64];
  const int tid = threadIdx.x;
  const int wave = tid >> 6, lane = tid & 63;
  const int lm = lane & 15, quad = lane >> 4;
  const int wr = wave >> 1, wc = wave & 1;
  const int m0 = blockIdx.y * 128, n0 = blockIdx.x * 128;
  f32x4 acc[4][4] = {};

  for (int kt = 0; kt < K; kt += 64) {
    for (int it = 0; it < 4; ++it) {
      int cl = it * 256 + tid;       // chunk id 0..1023 (16B chunks)
      int r = cl >> 3, pc = cl & 7;
      int cc = pc ^ (r & 7);         // source column-chunk (XOR swizzle, self-inverse)
      async_ld16(A + (m0 + r) * K + kt + cc * 8, As + cl * 8);
      async_ld16(Bt + (n0 + r) * K + kt + cc * 8, Bs + cl * 8);
    }
    __syncthreads();
    for (int kk = 0; kk < 64; kk += 32) {
      bf16x8 af[4], bfr[4];
      const int ccb = (kk >> 3) + quad;
      for (int i = 0; i < 4; ++i) {
        int row = wr * 64 + i * 16 + lm;
        af[i] = *(const bf16x8*)(As + row * 64 + (ccb ^ (row & 7)) * 8);
      }
      for (int j = 0; j < 4; ++j) {
        int row = wc * 64 + j * 16 + lm;
        bfr[j] = *(const bf16x8*)(Bs + row * 64 + (ccb ^ (row & 7)) * 8);
      }
      for (int i = 0; i < 4; ++i)
        for (int j = 0; j < 4; ++j)
          acc[i][j] = __builtin_amdgcn_mfma_f32_16x16x32_bf16(af[i], bfr[j], acc[i][j], 0, 0, 0);
    }
    __syncthreads();
  }

  if (EPI == 0) {
    const int qkv = n0 >> 10;                    // uniform per block (1024%128==0)
    const int hh = ((n0 + wc * 64) >> 6) & 15;   // uniform per wave
    for (int i = 0; i < 4; ++i) {
      const int gm0 = m0 + wr * 64 + i * 16 + quad * 4;
      const int b = gm0 >> 11, s0 = gm0 & 2047;  // 4 rows share b (gm0 % 4 == 0)
      for (int j = 0; j < 4; ++j) {
        const int e = j * 16 + lm;
        if (qkv == 2) {
          // V^T stored as f16 (attn PV uses mfma_16x16x16_f16)
          half4 pv = { (__fp16)acc[i][j][0], (__fp16)acc[i][j][1],
                       (__fp16)acc[i][j][2], (__fp16)acc[i][j][3] };
          *(half4*)(vt + (((b << 4) + hh) * 64 + e) * (size_t)S_ + s0) = pv;
        } else if (qkv == 0) {
          for (int r = 0; r < 4; ++r)
            qo[(((b << 4) + hh) * S_ + (s0 + r)) * (size_t)E_ + e] =
                (bf16)(acc[i][j][r] * QSCALE);   // fold 1/sqrt(E)*log2e here
        } else {
          for (int r = 0; r < 4; ++r)
            ko[(((b << 4) + hh) * S_ + (s0 + r)) * (size_t)E_ + e] = (bf16)acc[i][j][r];
        }
      }
    }
  } else {
    for (int i = 0; i < 4; ++i)
      for (int r = 0; r < 4; ++r) {
        const int gm = m0 + wr * 64 + i * 16 + quad * 4 + r;
        for (int j = 0; j < 4; ++j) {
          const int gn = n0 + wc * 64 + j * 16 + lm;
          outp[gm * (size_t)D_ + gn] = acc[i][j][r] + xres[gm * (size_t)D_ + gn];
        }
      }
  }
}

// -------- flash attention v5: register-resident P, shared K/V reads ----------
// Q,K: [B,H,S,E] bf16 (Q pre-scaled by log2e/8). Vt: [B,H,E,S] f16 bits.
// Block = (b,h, q-tile pair {qA, 31-qA}); wave owns 16 q-rows of each tile.
// S^T = K·Q^T (16x16x32) => C-layout col=sq(lane&15), row=sk(quad*4+reg),
// which IS the B-operand layout of mfma_f32_16x16x16f16 (k=quad*4+j) =>
// P feeds PV directly from registers (no LDS round-trip).
// K/V fragment reads are t-invariant => loaded once for both q-tiles.

__global__ __launch_bounds__(256, 4) void attn(
    const bf16* __restrict__ Q, const bf16* __restrict__ Kb,
    const bf16* __restrict__ Vt, bf16* __restrict__ Hd) {
  __shared__ __align__(16) bf16 Ks[2][64 * 64];
  __shared__ __align__(16) bf16 Vs[2][64 * 64];   // f16 bits
  const int tid = threadIdx.x;
  const int w = tid >> 6, lane = tid & 63;
  const int lm = lane & 15, quad = lane >> 4;
  const int l7 = lm & 7;
  const int qh = quad >> 1, qb1 = quad & 1;
  const int bi = blockIdx.x;
  const int bh = bi & 63;             // b*16+h
  const int qA = bi >> 6;             // 0..15
  const int qB = 31 - qA;             // paired tile: equal work per block
  const bf16* Qp = Q + (size_t)bh * S_ * E_;
  const bf16* Kp = Kb + (size_t)bh * S_ * E_;
  const bf16* Vp = Vt + (size_t)bh * E_ * S_;

  int qb[2], sq[2];
  bf16x8 qf[2][2];
  qb[0] = qA * 64 + w * 16;
  qb[1] = qB * 64 + w * 16;
#pragma unroll
  for (int t = 0; t < 2; ++t) {
    sq[t] = qb[t] + lm;
    qf[t][0] = *(const bf16x8*)(Qp + sq[t] * E_ + quad * 8);
    qf[t][1] = *(const bf16x8*)(Qp + sq[t] * E_ + 32 + quad * 8);
  }
  float ls[2] = { 0.0f, 0.0f };       // per-lane partial row sums
  f32x4 oacc[2][4] = {};

  for (int j = 0; j <= qB; ++j) {
    const int p = j & 1;
    const int sk0 = j * 64;
    // stage K tile [sk0..+63][0..63] and V^T tile [0..63][sk0..+63] (f16)
#pragma unroll
    for (int it = 0; it < 2; ++it) {
      int cl = it * 256 + tid;        // 0..511 16B chunks
      int r = cl >> 3, pc = cl & 7;
      int cc = pc ^ (r & 7);
      async_ld16(Kp + (sk0 + r) * E_ + cc * 8, &Ks[p][cl * 8]);
      async_ld16(Vp + (size_t)r * S_ + sk0 + cc * 8, &Vs[p][cl * 8]);
    }
    __syncthreads();                  // stage -> barrier (proven structure)

    const bool act0 = (j <= qA);      // block-uniform; t=1 always active

    // ---- QK: shared K fragments, both q-tiles ----
    f32x4 st[2][4] = {};
#pragma unroll
    for (int i = 0; i < 4; ++i) {
      const int row = i * 16 + lm;
      bf16x8 k0 = *(const bf16x8*)(&Ks[p][row * 64 + (quad ^ l7) * 8]);
      bf16x8 k1 = *(const bf16x8*)(&Ks[p][row * 64 + ((4 + quad) ^ l7) * 8]);
      st[1][i] = __builtin_amdgcn_mfma_f32_16x16x32_bf16(k0, qf[1][0], st[1][i], 0, 0, 0);
      st[1][i] = __builtin_amdgcn_mfma_f32_16x16x32_bf16(k1, qf[1][1], st[1][i], 0, 0, 0);
      if (act0) {
        st[0][i] = __builtin_amdgcn_mfma_f32_16x16x32_bf16(k0, qf[0][0], st[0][i], 0, 0, 0);
        st[0][i] = __builtin_amdgcn_mfma_f32_16x16x32_bf16(k1, qf[0][1], st[0][i], 0, 0, 0);
      }
    }

    // ---- softmax (max-free) + f16 pack, P stays in registers ----
    half4 pb[2][4];
#pragma unroll
    for (int t = 0; t < 2; ++t) {
      if (t == 0 && !act0) continue;              // uniform branch
      const bool diag = (t == 0) ? (j == qA) : (j == qB);
      if (diag) {                                 // mask sk>sq (d == w)
#pragma unroll
        for (int i = 0; i < 4; ++i) {
          const int base = (i - w) * 16 + quad * 4;
#pragma unroll
          for (int r = 0; r < 4; ++r)
            st[t][i][r] = (base + r > lm) ? -30000.0f : st[t][i][r];
        }
      }
#pragma unroll
      for (int i = 0; i < 4; ++i) {
        const float p0 = __builtin_amdgcn_exp2f(st[t][i][0]);
        const float p1 = __builtin_amdgcn_exp2f(st[t][i][1]);
        const float p2 = __builtin_amdgcn_exp2f(st[t][i][2]);
        const float p3 = __builtin_amdgcn_exp2f(st[t][i][3]);
        ls[t] += (p0 + p1) + (p2 + p3);
        half2 lo = __builtin_amdgcn_cvt_pkrtz(p0, p1);
        half2 hi = __builtin_amdgcn_cvt_pkrtz(p2, p3);
        pb[t][i] = __builtin_shufflevector(lo, hi, 0, 1, 2, 3);
      }
    }

    // ---- PV: O^T += V^T · P^T via 16x16x16 f16, shared V fragments ----
#pragma unroll
    for (int te = 0; te < 4; ++te) {
      const int row = te * 16 + lm;
#pragma unroll
      for (int i = 0; i < 4; ++i) {
        // lane's A-frag (V^T): k = i*16 + quad*4 .. +3, 8B swizzled read
        const int c = (2 * i + qh) ^ l7;
        half4 vf = *(const half4*)(&Vs[p][row * 64 + c * 8 + qb1 * 4]);
        oacc[1][te] = __builtin_amdgcn_mfma_f32_16x16x16f16(vf, pb[1][i], oacc[1][te], 0, 0, 0);
        if (act0)
          oacc[0][te] = __builtin_amdgcn_mfma_f32_16x16x16f16(vf, pb[0][i], oacc[0][te], 0, 0, 0);
      }
    }
  }

  const int b = bh >> 4, h = bh & 15;
#pragma unroll
  for (int t = 0; t < 2; ++t) {
    float rs = ls[t];
    rs += __shfl_xor(rs, 16);
    rs += __shfl_xor(rs, 32);
    const float inv = 1.0f / rs;
#pragma unroll
    for (int te = 0; te < 4; ++te) {
      bf16x4 ov = { (bf16)(oacc[t][te][0] * inv), (bf16)(oacc[t][te][1] * inv),
                    (bf16)(oacc[t][te][2] * inv), (bf16)(oacc[t][te][3] * inv) };
      *(bf16x4*)(&Hd[((size_t)b * S_ + sq[t]) * D_ + h * 64 + te * 16 + quad * 4]) = ov;
    }
  }
}

// ---------------- rowwise LayerNorm, in-place on f32 ----------------

__global__ __launch_bounds__(256) void lnorm(float* __restrict__ y,
                                             const float* __restrict__ gamma,
                                             const float* __restrict__ beta) {
  const int row = blockIdx.x, tid = threadIdx.x;
  float4v v = ((const float4v*)y)[row * 256 + tid];
  float s = v.x + v.y + v.z + v.w;
  float ss = v.x * v.x + v.y * v.y + v.z * v.z + v.w * v.w;
#pragma unroll
  for (int o = 1; o < 64; o <<= 1) { s += __shfl_xor(s, o); ss += __shfl_xor(ss, o); }
  __shared__ float sb[8];
  const int wv = tid >> 6, lane = tid & 63;
  if (lane == 0) { sb[wv] = s; sb[4 + wv] = ss; }
  __syncthreads();
  s = sb[0] + sb[1] + sb[2] + sb[3];
  ss = sb[4] + sb[5] + sb[6] + sb[7];
  const float mu = s * (1.0f / 1024.0f);
  const float var = ss * (1.0f / 1024.0f) - mu * mu;
  const float rstd = rsqrtf(var + 1e-3f);
  float4v g = ((const float4v*)gamma)[tid];
  float4v bb = ((const float4v*)beta)[tid];
  float4v o;
  o.x = (v.x - mu) * rstd * g.x + bb.x;
  o.y = (v.y - mu) * rstd * g.y + bb.y;
  o.z = (v.z - mu) * rstd * g.z + bb.z;
  o.w = (v.w - mu) * rstd * g.w + bb.w;
  ((float4v*)y)[row * 256 + tid] = o;
}

// ---------------- launch ----------------

extern "C" void kernel_launch(void* const* d_in, const int* in_sizes, int n_in,
                              void* d_out, int out_size, void* d_ws, size_t ws_size,
                              hipStream_t stream) {
  const float* x     = (const float*)d_in[0];
  const float* Wq    = (const float*)d_in[1];
  const float* Wk    = (const float*)d_in[2];
  const float* Wv    = (const float*)d_in[3];
  const float* Wo    = (const float*)d_in[4];
  const float* gamma = (const float*)d_in[5];
  const float* beta  = (const float*)d_in[6];
  float* out = (float*)d_out;

  char* ws = (char*)d_ws;
  bf16* xb    = (bf16*)(ws);                    // 16 MiB  (reused as heads)
  bf16* wqkvt = (bf16*)(ws + 16777216);         // 6 MiB
  bf16* wot   = (bf16*)(ws + 23068672);         // 2 MiB
  bf16* Qb    = (bf16*)(ws + 25165824);         // 16 MiB
  bf16* Kb    = (bf16*)(ws + 41943040);         // 16 MiB
  bf16* Vtb   = (bf16*)(ws + 58720256);         // 16 MiB (f16 bits)
  bf16* heads = xb;                             // alias: xb dead after gemm_qkv

  pack_x<<<M_ * D_ / 4 / 256, 256, 0, stream>>>(x, xb, M_ * D_ / 4);
  pack_wqkv<<<dim3(48, 16), 256, 0, stream>>>(Wq, Wk, Wv, wqkvt);
  pack_wo<<<dim3(16, 16), 256, 0, stream>>>(Wo, wot);
  gemm128<0><<<dim3(24, 64), 256, 0, stream>>>(xb, wqkvt, D_, Qb, Kb, Vtb, nullptr, nullptr);
  attn<<<64 * 16, 256, 0, stream>>>(Qb, Kb, Vtb, heads);
  gemm128<1><<<dim3(8, 64), 256, 0, stream>>>(heads, wot, D_, nullptr, nullptr, nullptr, x, out);
  lnorm<<<M_, 256, 0, stream>>>(out, gamma, beta);
}